// Round 1
// baseline (109.954 us; speedup 1.0000x reference)
//
#include <hip/hip_runtime.h>
#include <math.h>

#define BB 64
#define HH 30
#define WW 60
#define DD 64
#define NPIX 1800

// 16 col-bands / 8 row-bands = common refinement of the three pooling grids
__constant__ int c_rowband[HH] = {0,0,0,0,0,0, 1,1,1,1, 2,2, 3,3,3, 4,4,4, 5,5, 6,6,6,6, 7,7,7,7,7,7};
__constant__ int c_colband[WW] = {0,0,0,0,0,0, 1,1,1,1, 2,2, 3,3,3, 4,4,4, 5,5, 6,6,6,6, 7,7,7,7,7,7,
                                  8,8,8,8,8,8, 9,9,9,9, 10,10, 11,11,11, 12,12,12, 13,13, 14,14,14,14, 15,15,15,15,15,15};
// colband -> s0/s1 col-region index
__constant__ int c_s0col[16] = {0,1,1,2,2,3,3,4,5,6,6,7,7,8,8,9};
__constant__ int c_s1col[16] = {0,0,1,1,1,1,2,2,3,3,4,4,4,4,5,5};
// rowband -> s0/s1 row-region index
__constant__ int c_s0row[8] = {0,1,1,2,2,3,3,4};
__constant__ int c_s1row[8] = {0,0,1,1,1,1,2,2};
// colband -> [start,count) of colbands composing its s0/s1 col-region
__constant__ int c_s0st[16] = {0,1,1,3,3,5,5,7,8,9,9,11,11,13,13,15};
__constant__ int c_s0ct[16] = {1,2,2,2,2,2,2,1,1,2,2,2,2,2,2,1};
__constant__ int c_s1st[16] = {0,0,2,2,2,2,6,6,8,8,10,10,10,10,14,14};
__constant__ int c_s1ct[16] = {2,2,4,4,4,4,2,2,2,2,4,4,4,4,2,2};

// ---------------- K1: per-row colband sums (NO atomics, no memset needed)
// ----------------     + E/u/v/s weight precompute (blocks 1920..1983, R3-proven)
// rowsum[b][h][cb][d], cb in [0,16): sum of x over the colband's pixels in row h.
__global__ __launch_bounds__(256) void ka_rowsum(
    const float* __restrict__ x, const float* __restrict__ qk_w,
    const float* __restrict__ qk_b, float* __restrict__ rowsum,
    float* __restrict__ ET_ws, float* __restrict__ u_ws,
    float* __restrict__ v_ws, float* __restrict__ s_ws)
{
    const int t = threadIdx.x;

    if (blockIdx.x >= BB * HH) {
        // ET[e][d] = E[d][e] = sum_j Wq[j][d] * Wk[j][e]  (qk_w rows 0..63 = Wq, 64..127 = Wk)
        const int e = blockIdx.x - BB * HH;
        if (t < 64) {
            float acc = 0.f;
#pragma unroll 8
            for (int jj = 0; jj < 64; ++jj)
                acc += qk_w[jj * 64 + t] * qk_w[(64 + jj) * 64 + e];
            ET_ws[e * 64 + t] = acc;
        } else if (e == 0 && t >= 64 && t < 128) {   // u[d] = Wq^T bk
            const int d = t - 64;
            float acc = 0.f;
            for (int jj = 0; jj < 64; ++jj) acc += qk_w[jj * 64 + d] * qk_b[64 + jj];
            u_ws[d] = acc;
        } else if (e == 0 && t >= 128 && t < 192) {  // v[e] = Wk^T bq
            const int e2 = t - 128;
            float acc = 0.f;
            for (int jj = 0; jj < 64; ++jj) acc += qk_w[(64 + jj) * 64 + e2] * qk_b[jj];
            v_ws[e2] = acc;
        } else if (e == 0 && t == 192) {             // s = bq . bk
            float acc = 0.f;
            for (int jj = 0; jj < 64; ++jj) acc += qk_b[jj] * qk_b[64 + jj];
            s_ws[0] = acc;
        }
        return;
    }

    const int b = blockIdx.x / HH;
    const int h = blockIdx.x % HH;
    const int j = t & 63;
    const int g = t >> 6;     // wave -> 15-px column quarter

    const float* xrow = x + ((size_t)(b * NPIX + h * WW) + g * 15) * DD;
    float v[15];
#pragma unroll
    for (int i = 0; i < 15; ++i) v[i] = xrow[i * DD + j];

    float a0, a1, a2, a3;   // 4 colband sums within this wave's 15-px quarter
    if ((g & 1) == 0) {     // colband widths 6,4,2,3
        a0 = ((v[0]+v[1])+(v[2]+v[3]))+(v[4]+v[5]);
        a1 = (v[6]+v[7])+(v[8]+v[9]);
        a2 = v[10]+v[11];
        a3 = (v[12]+v[13])+v[14];
    } else {                // colband widths 3,2,4,6
        a0 = (v[0]+v[1])+v[2];
        a1 = v[3]+v[4];
        a2 = (v[5]+v[6])+(v[7]+v[8]);
        a3 = ((v[9]+v[10])+(v[11]+v[12]))+(v[13]+v[14]);
    }

    // coalesced stores: lanes j contiguous, colbands 4g..4g+3
    float* rs = rowsum + ((size_t)(b * HH + h) * 16 + 4 * g) * 64 + j;
    rs[0]   = a0;
    rs[64]  = a1;
    rs[128] = a2;
    rs[192] = a3;
}

// ---------------- K2: per-(b,rowband) cell vectors G + offsets c ----------------
// grid = BB*8, block = 256. First reduces the <=20 relevant rowsum rows into the
// three per-scale row aggregates (coalesced float4 loads, block-uniform predicates),
// then builds XC and runs the register-ET MFMA-free dot exactly as before.
__global__ __launch_bounds__(256) void kb_G(
    const float* __restrict__ score_w, const float* __restrict__ score_b,
    const float* __restrict__ rowsum, const float* __restrict__ ET_ws,
    const float* __restrict__ u_ws, const float* __restrict__ v_ws,
    const float* __restrict__ s_ws, float* __restrict__ G, float* __restrict__ cc)
{
    __shared__ float ETs[4096];     // 16 KB
    __shared__ float S0L[1024];     // per-scale row aggregates, [cb][d]
    __shared__ float S1L[1024];
    __shared__ float S2L[1024];
    __shared__ float XC[16 * 64];   // 4 KB
    __shared__ float ul[64], vl[64];

    const int b = blockIdx.x >> 3;
    const int rb = blockIdx.x & 7;
    const int t = threadIdx.x;
    const int lane = t & 63;
    const int g = t >> 6;

    for (int i = t; i < 4096; i += 256) ETs[i] = ET_ws[i];
    if (t < 64) ul[t] = u_ws[t];
    else if (t < 128) vl[t - 64] = v_ws[t - 64];

    // row ranges of the three scales at this rowband
    const int s0r = c_s0row[rb], s1r = c_s1row[rb], s2r = rb >> 2;
    const int h00 = 6 * s0r,  h01 = h00 + 6;
    const int h10 = 10 * s1r, h11 = h10 + 10;
    const int h20 = 15 * s2r, h21 = h20 + 15;
    int hmin = h00 < h10 ? h00 : h10; if (h20 < hmin) hmin = h20;
    int hmax = h01 > h11 ? h01 : h11; if (h21 > hmax) hmax = h21;

    // each thread owns float4 element t of the 1024-float [16][64] row layout
    float4 a0 = {0.f,0.f,0.f,0.f}, a1 = {0.f,0.f,0.f,0.f}, a2 = {0.f,0.f,0.f,0.f};
    const float4* rsb = (const float4*)(rowsum + (size_t)b * HH * 1024);
    for (int h = hmin; h < hmax; ++h) {
        const float4 rv = rsb[h * 256 + t];
        if (h >= h00 && h < h01) { a0.x += rv.x; a0.y += rv.y; a0.z += rv.z; a0.w += rv.w; }
        if (h >= h10 && h < h11) { a1.x += rv.x; a1.y += rv.y; a1.z += rv.z; a1.w += rv.w; }
        if (h >= h20 && h < h21) { a2.x += rv.x; a2.y += rv.y; a2.z += rv.z; a2.w += rv.w; }
    }
    ((float4*)S0L)[t] = a0;
    ((float4*)S1L)[t] = a1;
    ((float4*)S2L)[t] = a2;
    __syncthreads();

    // XC[cb][d] = w0n * s0region + w1n * s1region + w2n * s2region
    {
        const float w0n = score_w[0] * (1.0f / 36.0f);
        const float w1n = score_w[1] * (1.0f / 100.0f);
        const float w2n = score_w[2] * (1.0f / 225.0f);
        const int cb = (4 * t) >> 6;
        const int d0 = (4 * t) & 63;
        const int st0 = c_s0st[cb], ct0 = c_s0ct[cb];
        const int st1 = c_s1st[cb], ct1 = c_s1ct[cb];
        const int st2 = cb & ~3;
#pragma unroll
        for (int k = 0; k < 4; ++k) {
            const int d = d0 + k;
            float s0v = 0.f;
            for (int c = 0; c < ct0; ++c) s0v += S0L[(st0 + c) * 64 + d];
            float s1v = 0.f;
            for (int c = 0; c < ct1; ++c) s1v += S1L[(st1 + c) * 64 + d];
            const float s2v = S2L[st2 * 64 + d] + S2L[(st2 + 1) * 64 + d]
                            + S2L[(st2 + 2) * 64 + d] + S2L[(st2 + 3) * 64 + d];
            XC[cb * 64 + d] = w0n * s0v + w1n * s1v + w2n * s2v;
        }
    }
    __syncthreads();

    float et[64];
#pragma unroll
    for (int e = 0; e < 64; ++e) et[e] = ETs[e * 64 + lane];  // 2-way aliasing = free

    const float wsum = score_w[0] + score_w[1] + score_w[2];
    const float sv = s_ws[0];
    const float sb = score_b[0];
    const float uval = ul[lane];
    const float vval = vl[lane];

#pragma unroll
    for (int ci = 0; ci < 4; ++ci) {
        const int cb = g * 4 + ci;
        const float4* xc4 = (const float4*)(XC + cb * 64);
        float acc = 0.f;
#pragma unroll
        for (int q = 0; q < 16; ++q) {
            const float4 xv = xc4[q];     // wave-uniform -> broadcast
            acc += xv.x * et[4*q] + xv.y * et[4*q+1] + xv.z * et[4*q+2] + xv.w * et[4*q+3];
        }
        G[(size_t)b * 8192 + rb * 1024 + cb * 64 + lane] = 0.125f * (acc + wsum * uval);

        float pv = vval * XC[cb * 64 + lane];
        pv += __shfl_xor(pv, 1, 64);  pv += __shfl_xor(pv, 2, 64);
        pv += __shfl_xor(pv, 4, 64);  pv += __shfl_xor(pv, 8, 64);
        pv += __shfl_xor(pv, 16, 64); pv += __shfl_xor(pv, 32, 64);
        if (lane == 0) cc[b * 128 + rb * 16 + cb] = 0.125f * (pv + wsum * sv) + sb;
    }
}

// ---------------- K3: per-pixel dot + gumbel-sigmoid mask (R2-proven) ----------------
__global__ __launch_bounds__(256) void kc_mask(
    const float* __restrict__ x, const float* __restrict__ G,
    const float* __restrict__ cc, const float* __restrict__ noise_x,
    const float* __restrict__ noise_r, float* __restrict__ out)
{
    __shared__ float Grow[1024];
    __shared__ float crow[16];
    __shared__ float attnv[64];
    __shared__ int cbt[64];

    const int b = blockIdx.x / HH;
    const int h = blockIdx.x % HH;
    const int t = threadIdx.x;
    const int lane = t & 63;
    const int g = t >> 6;
    const int rb = c_rowband[h];

    ((float4*)Grow)[t] = ((const float4*)(G + (size_t)b * 8192 + rb * 1024))[t];
    if (t < 16) crow[t] = cc[b * 128 + rb * 16 + t];
    if (t < 60) cbt[t] = c_colband[t];
    __syncthreads();

    const float4* x4 = (const float4*)(x + (size_t)(b * NPIX + h * WW) * DD);
    const int f = lane & 15;
    const int pg = lane >> 4;
#pragma unroll
    for (int i = 0; i < 4; ++i) {
        const int pl = i * 4 + pg;
        if (pl < 15) {
            const int p = g * 15 + pl;
            const int cb = cbt[p];
            const float4 xv = x4[p * 16 + f];
            const float4 gv = ((const float4*)Grow)[cb * 16 + f];
            float s = xv.x * gv.x + xv.y * gv.y + xv.z * gv.z + xv.w * gv.w;
            s += __shfl_xor(s, 1, 64);
            s += __shfl_xor(s, 2, 64);
            s += __shfl_xor(s, 4, 64);
            s += __shfl_xor(s, 8, 64);
            if (f == 0) attnv[p] = s + crow[cb];
        }
    }
    __syncthreads();

    if (t < 60) {
        const int pix = b * NPIX + h * WW + t;
        const float a = attnv[t];
        const float sg = 1.0f / (1.0f + expf(-a));
        const float gx = logf(sg + 1e-8f);
        const float gr = logf(1.0f - sg + 1e-8f);
        const float ux = noise_x[pix];
        const float ur = noise_r[pix];
        const float nx = -logf(-logf(ux + 1e-8f) + 1e-8f);
        const float nr = -logf(-logf(ur + 1e-8f) + 1e-8f);
        const float INV_T = 1.0f / (0.03f + 1e-8f);
        const float A = (gx + nx) * INV_T;
        const float R = (gr + nr) * INV_T;
        out[pix] = 1.0f / (1.0f + expf(R - A));
    }
}

extern "C" void kernel_launch(void* const* d_in, const int* in_sizes, int n_in,
                              void* d_out, int out_size, void* d_ws, size_t ws_size,
                              hipStream_t stream)
{
    const float* x       = (const float*)d_in[0];
    const float* qk_w    = (const float*)d_in[1];
    const float* qk_b    = (const float*)d_in[2];
    const float* score_w = (const float*)d_in[3];
    const float* score_b = (const float*)d_in[4];
    const float* noise_x = (const float*)d_in[5];
    const float* noise_r = (const float*)d_in[6];
    float* out = (float*)d_out;

    float* rowsum = (float*)d_ws;                         // 64*30*16*64 = 1,966,080 floats (7.9 MB)
    float* G      = rowsum + (size_t)BB * HH * 16 * 64;   // 64*128*64 = 524288 floats (2 MB)
    float* cc     = G + (size_t)BB * 128 * 64;            // 8192
    float* ET_ws  = cc + BB * 128;                        // 4096
    float* u_ws   = ET_ws + 4096;                         // 64
    float* v_ws   = u_ws + 64;                            // 64
    float* s_ws   = v_ws + 64;                            // 1
    // total ~10 MB; every word fully written before read -> no memset needed

    ka_rowsum<<<BB * HH + 64, 256, 0, stream>>>(x, qk_w, qk_b, rowsum, ET_ws, u_ws, v_ws, s_ws);
    kb_G<<<BB * 8, 256, 0, stream>>>(score_w, score_b, rowsum, ET_ws, u_ws, v_ws, s_ws, G, cc);
    kc_mask<<<BB * HH, 256, 0, stream>>>(x, G, cc, noise_x, noise_r, out);
}